// Round 17
// baseline (146.264 us; speedup 1.0000x reference)
//
#include <hip/hip_runtime.h>
#include <cstdint>
#include <cstddef>

// Linear attention: B=4 N=4096 C=768 H=12 d=64
// Pipeline: fused cast->bf16, GEMM1 128x128 BK=64 m97-style (x@Wqkv^T, fused
// phi), kv/ksum partials (32 chunks, LDS-f32-staged), widened reduce
// (kv->bf16), y via MFMA, GEMM2 128x128 BK=64 (y@Wproj^T + bias).
//
// Ledger: BK=64 2-barrier BEATS 8-phase(118), ring(114), dbuf(103),
// BK=32(108), kk-split(113), BK=96(+8). __launch_bounds__(256,4) on gemm128:
// 92->77.6us (VGPR 80->64, VALUBusy 44->26%, +1 block/CU). kv: LDS-f32
// staging -25us (r13); fdot2 FAILED numerics (r14); f32x2 pack neutral (r15).
// r17: kv_partial 16->32 chunks (3->5 blocks/CU, LDS-capped) for TLP.

typedef __attribute__((ext_vector_type(8))) short bf16x8;
typedef __attribute__((ext_vector_type(4))) float f32x4;
typedef __attribute__((ext_vector_type(2))) float f32x2;

__device__ __forceinline__ unsigned short f2bf(float f) {
  uint32_t u = __builtin_bit_cast(uint32_t, f);
  u += 0x7FFFu + ((u >> 16) & 1u);  // RNE
  return (unsigned short)(u >> 16);
}
__device__ __forceinline__ float bf2f(unsigned short h) {
  uint32_t u = ((uint32_t)h) << 16;
  return __builtin_bit_cast(float, u);
}

__global__ __launch_bounds__(256) void cast3_kernel(
    const float* __restrict__ a, const float* __restrict__ b,
    const float* __restrict__ c, unsigned short* __restrict__ oa,
    unsigned short* __restrict__ ob, unsigned short* __restrict__ oc,
    int na4, int nb4, int nc4) {
  int i = blockIdx.x * 256 + threadIdx.x;
  const float* src;
  unsigned short* dst;
  if (i < na4) {
    src = a; dst = oa;
  } else if (i < na4 + nb4) {
    i -= na4; src = b; dst = ob;
  } else if (i < na4 + nb4 + nc4) {
    i -= na4 + nb4; src = c; dst = oc;
  } else {
    return;
  }
  float4 v = reinterpret_cast<const float4*>(src)[i];
  ushort4 o;
  o.x = f2bf(v.x); o.y = f2bf(v.y); o.z = f2bf(v.z); o.w = f2bf(v.w);
  reinterpret_cast<ushort4*>(dst)[i] = o;
}

#define GLOAD_LDS16(g, s)                                                     \
  __builtin_amdgcn_global_load_lds(                                           \
      (const __attribute__((address_space(1))) void*)(g),                     \
      (__attribute__((address_space(3))) void*)(s), 16, 0, 0)

__device__ __forceinline__ int xcd_swizzle(int lin, int nwg) {
  const int q = nwg >> 3, r = nwg & 7;
  const int xcd = lin & 7, idx = lin >> 3;
  return (xcd < r ? xcd * (q + 1) : r * (q + 1) + (xcd - r) * q) + idx;
}

// ============================================================================
// PROVEN: 128x128 tile, BK=64, 4 waves, 4x4 16x16x32 frags, global_load_lds
// width-16, plain __syncthreads (2/K-step), XOR chunk swizzle both-sides
// (rule #21), bijective XCD swizzle (m204). __launch_bounds__(256,4): caps
// regs -> 64 arch VGPR, 4 blocks/CU, VALUBusy halved (r16: 92->77.6us).
// ============================================================================
template <int PHI_COLS, bool OUT_BF16, bool BIAS>
__global__ __launch_bounds__(256, 4) void gemm128(
    const unsigned short* __restrict__ A, const unsigned short* __restrict__ B,
    void* __restrict__ Cout, const float* __restrict__ bias, int M, int N, int K) {
  __shared__ unsigned short As[128 * 64];
  __shared__ unsigned short Bs[128 * 64];
  const int t = threadIdx.x;
  const int w = t >> 6;
  const int l = t & 63;
  const int r16 = l & 15;
  const int c4 = l >> 4;

  const int nx = gridDim.x;
  const int lin = xcd_swizzle(blockIdx.y * nx + blockIdx.x, gridDim.x * gridDim.y);
  const int m0 = (lin / nx) * 128;
  const int n0 = (lin % nx) * 128;

  const int srow = t >> 3;                      // 0..31
  const int schunk = (t & 7) ^ ((t >> 3) & 7);  // pre-swizzled source chunk
  const unsigned short* gA = A + (size_t)(m0 + srow) * K + schunk * 8;
  const unsigned short* gB = B + (size_t)(n0 + srow) * K + schunk * 8;
  const int lbase = w * 512;

  const int wm = (w >> 1) * 64;
  const int wn = (w & 1) * 64;

  f32x4 acc[4][4] = {};

  for (int k0 = 0; k0 < K; k0 += 64) {
#pragma unroll
    for (int i = 0; i < 4; ++i) {
      GLOAD_LDS16(gA + k0 + (size_t)i * 32 * K, &As[lbase + i * 2048]);
      GLOAD_LDS16(gB + k0 + (size_t)i * 32 * K, &Bs[lbase + i * 2048]);
    }
    __syncthreads();
#pragma unroll
    for (int kk = 0; kk < 2; ++kk) {
      bf16x8 af[4], bfr[4];
#pragma unroll
      for (int mi = 0; mi < 4; ++mi) {
        const int R = wm + mi * 16 + r16;
        const int ch = (kk * 4 + c4) ^ (R & 7);
        af[mi] = *reinterpret_cast<const bf16x8*>(&As[R * 64 + ch * 8]);
      }
#pragma unroll
      for (int ni = 0; ni < 4; ++ni) {
        const int R = wn + ni * 16 + r16;
        const int ch = (kk * 4 + c4) ^ (R & 7);
        bfr[ni] = *reinterpret_cast<const bf16x8*>(&Bs[R * 64 + ch * 8]);
      }
#pragma unroll
      for (int mi = 0; mi < 4; ++mi)
#pragma unroll
        for (int ni = 0; ni < 4; ++ni)
          acc[mi][ni] = __builtin_amdgcn_mfma_f32_16x16x32_bf16(af[mi], bfr[ni], acc[mi][ni], 0, 0, 0);
    }
    __syncthreads();
  }

  // epilogue: C/D layout col=lane&15, row=(lane>>4)*4+reg (m89/m91 verified)
  const int rbase = c4 * 4;
#pragma unroll
  for (int mi = 0; mi < 4; ++mi) {
    const int row = m0 + wm + mi * 16 + rbase;
#pragma unroll
    for (int ni = 0; ni < 4; ++ni) {
      const int col = n0 + wn + ni * 16 + r16;
      float bv = 0.0f;
      if constexpr (BIAS) bv = bias[col];
      f32x4 v = acc[mi][ni];
#pragma unroll
      for (int r = 0; r < 4; ++r) {
        float x = v[r] + bv;
        if constexpr (PHI_COLS > 0) {
          if (col < PHI_COLS) x = (x > 0.0f) ? (x + 1.0f) : __expf(x);  // elu+1
        }
        if constexpr (OUT_BF16)
          ((unsigned short*)Cout)[(size_t)(row + r) * N + col] = f2bf(x);
        else
          ((float*)Cout)[(size_t)(row + r) * N + col] = x;
      }
    }
  }
}

// ============================================================================
// kv[m,d] = sum_n k[n,d]*v[n,m]; ksum[d] = sum_n k[n,d].
// 32 chunks of 128 n per (b,h) -> 1536 blocks, 5 blocks/CU (LDS-capped).
// LDS-f32 staging of 64-n sub-tiles (cvt once per block, r13's -25us win).
// ============================================================================
__global__ __launch_bounds__(256) void kv_partial_kernel(
    const unsigned short* __restrict__ qkv, float* __restrict__ kv_part,
    float* __restrict__ ksum_part) {
  __shared__ float ks32[64][64];  // [n][d] f32, 16KB
  __shared__ float vs32[64][64];  // [n][m] f32, 16KB
  const int bh = blockIdx.x;     // 48
  const int chunk = blockIdx.y;  // 32 (128 n each)
  const int b = bh / 12, h = bh % 12;
  const int t = threadIdx.x;
  const int tm = (t >> 4) * 4;
  const int td = (t & 15) * 4;
  const unsigned short* base =
      qkv + ((size_t)(b * 4096 + chunk * 128)) * 2304 + h * 64;

  f32x2 acc2[4][2] = {};
  f32x2 kss[2] = {};

  for (int sub = 0; sub < 2; ++sub) {
#pragma unroll
    for (int s = t; s < 512; s += 256) {
      const int nl = s >> 3;
      const int oct = s & 7;
      const unsigned short* row = base + (size_t)(sub * 64 + nl) * 2304 + oct * 8;
      bf16x8 ku = *reinterpret_cast<const bf16x8*>(row + 768);   // k
      bf16x8 vu = *reinterpret_cast<const bf16x8*>(row + 1536);  // v
      float* kd = &ks32[nl][oct * 8];
      float* vd = &vs32[nl][oct * 8];
#pragma unroll
      for (int j = 0; j < 8; ++j) {
        kd[j] = bf2f((unsigned short)ku[j]);
        vd[j] = bf2f((unsigned short)vu[j]);
      }
    }
    __syncthreads();
#pragma unroll 8
    for (int n = 0; n < 64; ++n) {
      float4 kf = *reinterpret_cast<const float4*>(&ks32[n][td]);
      float4 vf = *reinterpret_cast<const float4*>(&vs32[n][tm]);
      f32x2 k0; k0[0] = kf.x; k0[1] = kf.y;
      f32x2 k1; k1[0] = kf.z; k1[1] = kf.w;
      const float va[4] = {vf.x, vf.y, vf.z, vf.w};
#pragma unroll
      for (int i = 0; i < 4; ++i) {
        f32x2 vd2; vd2[0] = va[i]; vd2[1] = va[i];
        acc2[i][0] += vd2 * k0;
        acc2[i][1] += vd2 * k1;
      }
      kss[0] += k0;
      kss[1] += k1;
    }
    __syncthreads();
  }

  float* kvp = kv_part + ((size_t)(bh * 32 + chunk)) * 4096;
#pragma unroll
  for (int i = 0; i < 4; ++i) {
    float4 o;
    o.x = acc2[i][0][0]; o.y = acc2[i][0][1];
    o.z = acc2[i][1][0]; o.w = acc2[i][1][1];
    *reinterpret_cast<float4*>(&kvp[(tm + i) * 64 + td]) = o;
  }
  if (tm == 0) {
    float* ksp = ksum_part + (size_t)(bh * 32 + chunk) * 64;
    float4 o;
    o.x = kss[0][0]; o.y = kss[0][1]; o.z = kss[1][0]; o.w = kss[1][1];
    *reinterpret_cast<float4*>(&ksp[td]) = o;
  }
}

// widened reduce: grid (48,4); float4 loads; kv emitted bf16, ksum f32.
__global__ __launch_bounds__(256) void kv_reduce_kernel(
    const float* __restrict__ kv_part, const float* __restrict__ ksum_part,
    unsigned short* __restrict__ kvb, float* __restrict__ ksum) {
  const int bh = blockIdx.x;
  const int seg = blockIdx.y;
  const int t = threadIdx.x;
  const int e = seg * 1024 + t * 4;
  float4 s = {0.f, 0.f, 0.f, 0.f};
#pragma unroll
  for (int c = 0; c < 32; ++c) {
    float4 v = *reinterpret_cast<const float4*>(
        &kv_part[((size_t)(bh * 32 + c)) * 4096 + e]);
    s.x += v.x; s.y += v.y; s.z += v.z; s.w += v.w;
  }
  ushort4 o;
  o.x = f2bf(s.x); o.y = f2bf(s.y); o.z = f2bf(s.z); o.w = f2bf(s.w);
  *reinterpret_cast<ushort4*>(&kvb[(size_t)bh * 4096 + e]) = o;
  if (seg == 0 && t < 64) {
    float ss = 0.f;
#pragma unroll
    for (int c = 0; c < 32; ++c) ss += ksum_part[(size_t)(bh * 32 + c) * 64 + t];
    ksum[bh * 64 + t] = ss;
  }
}

// y[n,m] = z[n] * sum_d q[n,d] kv[m,d], z[n]=1/(q[n,:].ksum+eps), via MFMA.
__global__ __launch_bounds__(256) void y_mfma_kernel(
    const unsigned short* __restrict__ qkv, const unsigned short* __restrict__ kvb,
    const float* __restrict__ ksum, unsigned short* __restrict__ ybf) {
  __shared__ unsigned short Qs[128 * 64];
  __shared__ unsigned short KVs[64 * 64];
  __shared__ float zs[128];
  const int bh = blockIdx.x;
  const int n0 = blockIdx.y * 128;
  const int b = bh / 12, h = bh % 12;
  const int t = threadIdx.x;
  const int w = t >> 6;
  const int l = t & 63;
  const int r16 = l & 15;
  const int c4 = l >> 4;

  const int srow = t >> 3;
  const int schunk = (t & 7) ^ ((t >> 3) & 7);
  const unsigned short* gQ =
      qkv + ((size_t)(b * 4096 + n0 + srow)) * 2304 + h * 64 + schunk * 8;
  const unsigned short* gKV = kvb + (size_t)bh * 4096 + srow * 64 + schunk * 8;
  const int lbase = w * 512;
#pragma unroll
  for (int i = 0; i < 4; ++i)
    GLOAD_LDS16(gQ + (size_t)i * 32 * 2304, &Qs[lbase + i * 2048]);
#pragma unroll
  for (int i = 0; i < 2; ++i)
    GLOAD_LDS16(gKV + i * 32 * 64, &KVs[lbase + i * 2048]);
  __syncthreads();

  const int wr = w * 32;
  f32x4 acc[2][4] = {};
#pragma unroll
  for (int kk = 0; kk < 2; ++kk) {
    bf16x8 af[2], bfr[4];
#pragma unroll
    for (int mi = 0; mi < 2; ++mi) {
      const int R = wr + mi * 16 + r16;
      const int ch = (kk * 4 + c4) ^ (R & 7);
      af[mi] = *reinterpret_cast<const bf16x8*>(&Qs[R * 64 + ch * 8]);
    }
#pragma unroll
    for (int ni = 0; ni < 4; ++ni) {
      const int R = ni * 16 + r16;
      const int ch = (kk * 4 + c4) ^ (R & 7);
      bfr[ni] = *reinterpret_cast<const bf16x8*>(&KVs[R * 64 + ch * 8]);
    }
#pragma unroll
    for (int mi = 0; mi < 2; ++mi)
#pragma unroll
      for (int ni = 0; ni < 4; ++ni)
        acc[mi][ni] = __builtin_amdgcn_mfma_f32_16x16x32_bf16(af[mi], bfr[ni], acc[mi][ni], 0, 0, 0);
  }

  if (t < 128) {
    const float* ks = ksum + bh * 64;
    float s = 0.f;
#pragma unroll
    for (int c = 0; c < 8; ++c) {
      bf16x8 qv = *reinterpret_cast<const bf16x8*>(&Qs[t * 64 + ((c ^ (t & 7)) * 8)]);
#pragma unroll
      for (int j = 0; j < 8; ++j) s += bf2f((unsigned short)qv[j]) * ks[c * 8 + j];
    }
    zs[t] = 1.0f / (s + 1e-6f);
  }
  __syncthreads();

  unsigned short* ybase = ybf + ((size_t)(b * 4096 + n0)) * 768 + h * 64;
#pragma unroll
  for (int mi = 0; mi < 2; ++mi) {
#pragma unroll
    for (int ni = 0; ni < 4; ++ni) {
      const int col = ni * 16 + r16;
      f32x4 v = acc[mi][ni];
#pragma unroll
      for (int r = 0; r < 4; ++r) {
        const int row = wr + mi * 16 + c4 * 4 + r;
        ybase[(size_t)row * 768 + col] = f2bf(v[r] * zs[row]);
      }
    }
  }
}

extern "C" void kernel_launch(void* const* d_in, const int* in_sizes, int n_in,
                              void* d_out, int out_size, void* d_ws, size_t ws_size,
                              hipStream_t stream) {
  const float* x = (const float*)d_in[0];
  const float* Wqkv = (const float*)d_in[1];
  const float* Wproj = (const float*)d_in[2];
  const float* bproj = (const float*)d_in[3];
  float* out = (float*)d_out;

  const int M = 16384;
  const int C = 768;
  const int N1 = 2304;

  char* ws = (char*)d_ws;
  size_t off = 0;
  unsigned short* xb = (unsigned short*)(ws + off);  off += (size_t)M * C * 2;
  unsigned short* wqb = (unsigned short*)(ws + off); off += (size_t)N1 * C * 2;
  unsigned short* wpb = (unsigned short*)(ws + off); off += (size_t)C * C * 2;
  unsigned short* qkvb = (unsigned short*)(ws + off); off += (size_t)M * N1 * 2;
  unsigned short* kvb = (unsigned short*)(ws + off); off += (size_t)48 * 4096 * 2;
  float* ksum = (float*)(ws + off);      off += (size_t)48 * 64 * 4;
  unsigned short* yb = (unsigned short*)(ws + off); off += (size_t)M * C * 2;
  float* ksum_part = (float*)(ws + off); off += (size_t)48 * 32 * 64 * 4;
  // kv_part overlays xb (dead after GEMM1): 48*32*4096*4 = 25.17MB == xb size
  float* kv_part = (float*)xb;

  const int na4 = M * C / 4, nb4 = N1 * C / 4, nc4 = C * C / 4;
  cast3_kernel<<<(na4 + nb4 + nc4 + 255) / 256, 256, 0, stream>>>(
      x, Wqkv, Wproj, xb, wqb, wpb, na4, nb4, nc4);

  // qkv = x @ Wqkv^T, phi fused on q,k columns, bf16 out
  gemm128<1536, true, false>
      <<<dim3(N1 / 128, M / 128), 256, 0, stream>>>(xb, wqb, qkvb, nullptr, M, N1, C);

  kv_partial_kernel<<<dim3(48, 32), 256, 0, stream>>>(qkvb, kv_part, ksum_part);
  kv_reduce_kernel<<<dim3(48, 4), 256, 0, stream>>>(kv_part, ksum_part, kvb, ksum);
  y_mfma_kernel<<<dim3(48, 32), 256, 0, stream>>>(qkvb, kvb, ksum, yb);

  // out = y @ Wproj^T + b, fp32 out
  gemm128<0, false, true>
      <<<dim3(C / 128, M / 128), 256, 0, stream>>>(yb, wpb, out, bproj, M, C, C);
}

// Round 18
// 145.245 us; speedup vs baseline: 1.0070x; 1.0070x over previous
//
#include <hip/hip_runtime.h>
#include <cstdint>
#include <cstddef>

// Linear attention: B=4 N=4096 C=768 H=12 d=64
// FINAL (round-16 configuration, session optimum 145.0us):
// fused cast->bf16, GEMM1 128x128 BK=64 m97-style + __launch_bounds__(256,4)
// (x@Wqkv^T, fused phi), kv/ksum partials (16 chunks, LDS-f32-staged),
// widened reduce (kv->bf16), y via MFMA, GEMM2 same-structure (y@Wproj^T+b).
//
// Ledger: BK=64 2-barrier BEATS 8-phase(118), ring(114), dbuf(103),
// BK=32(108), kk-split(113), BK=96(+8). __launch_bounds__(256,4) on gemm128:
// 92->77.6us (VGPR 80->64, VALUBusy 44->26%, +1 block/CU). kv: LDS-f32
// staging -25us (r13); fdot2 FAILED numerics (r14); f32x2 pack neutral
// (r15); 32-chunk TLP neutral (r17, memory-bound floor). Session: 238->145us.

typedef __attribute__((ext_vector_type(8))) short bf16x8;
typedef __attribute__((ext_vector_type(4))) float f32x4;
typedef __attribute__((ext_vector_type(2))) float f32x2;

__device__ __forceinline__ unsigned short f2bf(float f) {
  uint32_t u = __builtin_bit_cast(uint32_t, f);
  u += 0x7FFFu + ((u >> 16) & 1u);  // RNE
  return (unsigned short)(u >> 16);
}
__device__ __forceinline__ float bf2f(unsigned short h) {
  uint32_t u = ((uint32_t)h) << 16;
  return __builtin_bit_cast(float, u);
}

__global__ __launch_bounds__(256) void cast3_kernel(
    const float* __restrict__ a, const float* __restrict__ b,
    const float* __restrict__ c, unsigned short* __restrict__ oa,
    unsigned short* __restrict__ ob, unsigned short* __restrict__ oc,
    int na4, int nb4, int nc4) {
  int i = blockIdx.x * 256 + threadIdx.x;
  const float* src;
  unsigned short* dst;
  if (i < na4) {
    src = a; dst = oa;
  } else if (i < na4 + nb4) {
    i -= na4; src = b; dst = ob;
  } else if (i < na4 + nb4 + nc4) {
    i -= na4 + nb4; src = c; dst = oc;
  } else {
    return;
  }
  float4 v = reinterpret_cast<const float4*>(src)[i];
  ushort4 o;
  o.x = f2bf(v.x); o.y = f2bf(v.y); o.z = f2bf(v.z); o.w = f2bf(v.w);
  reinterpret_cast<ushort4*>(dst)[i] = o;
}

#define GLOAD_LDS16(g, s)                                                     \
  __builtin_amdgcn_global_load_lds(                                           \
      (const __attribute__((address_space(1))) void*)(g),                     \
      (__attribute__((address_space(3))) void*)(s), 16, 0, 0)

__device__ __forceinline__ int xcd_swizzle(int lin, int nwg) {
  const int q = nwg >> 3, r = nwg & 7;
  const int xcd = lin & 7, idx = lin >> 3;
  return (xcd < r ? xcd * (q + 1) : r * (q + 1) + (xcd - r) * q) + idx;
}

// ============================================================================
// PROVEN: 128x128 tile, BK=64, 4 waves, 4x4 16x16x32 frags, global_load_lds
// width-16, plain __syncthreads (2/K-step), XOR chunk swizzle both-sides
// (rule #21), bijective XCD swizzle (m204). __launch_bounds__(256,4): caps
// regs -> 64 arch VGPR, 4 blocks/CU, VALUBusy halved (r16: 92->77.6us).
// ============================================================================
template <int PHI_COLS, bool OUT_BF16, bool BIAS>
__global__ __launch_bounds__(256, 4) void gemm128(
    const unsigned short* __restrict__ A, const unsigned short* __restrict__ B,
    void* __restrict__ Cout, const float* __restrict__ bias, int M, int N, int K) {
  __shared__ unsigned short As[128 * 64];
  __shared__ unsigned short Bs[128 * 64];
  const int t = threadIdx.x;
  const int w = t >> 6;
  const int l = t & 63;
  const int r16 = l & 15;
  const int c4 = l >> 4;

  const int nx = gridDim.x;
  const int lin = xcd_swizzle(blockIdx.y * nx + blockIdx.x, gridDim.x * gridDim.y);
  const int m0 = (lin / nx) * 128;
  const int n0 = (lin % nx) * 128;

  const int srow = t >> 3;                      // 0..31
  const int schunk = (t & 7) ^ ((t >> 3) & 7);  // pre-swizzled source chunk
  const unsigned short* gA = A + (size_t)(m0 + srow) * K + schunk * 8;
  const unsigned short* gB = B + (size_t)(n0 + srow) * K + schunk * 8;
  const int lbase = w * 512;

  const int wm = (w >> 1) * 64;
  const int wn = (w & 1) * 64;

  f32x4 acc[4][4] = {};

  for (int k0 = 0; k0 < K; k0 += 64) {
#pragma unroll
    for (int i = 0; i < 4; ++i) {
      GLOAD_LDS16(gA + k0 + (size_t)i * 32 * K, &As[lbase + i * 2048]);
      GLOAD_LDS16(gB + k0 + (size_t)i * 32 * K, &Bs[lbase + i * 2048]);
    }
    __syncthreads();
#pragma unroll
    for (int kk = 0; kk < 2; ++kk) {
      bf16x8 af[4], bfr[4];
#pragma unroll
      for (int mi = 0; mi < 4; ++mi) {
        const int R = wm + mi * 16 + r16;
        const int ch = (kk * 4 + c4) ^ (R & 7);
        af[mi] = *reinterpret_cast<const bf16x8*>(&As[R * 64 + ch * 8]);
      }
#pragma unroll
      for (int ni = 0; ni < 4; ++ni) {
        const int R = wn + ni * 16 + r16;
        const int ch = (kk * 4 + c4) ^ (R & 7);
        bfr[ni] = *reinterpret_cast<const bf16x8*>(&Bs[R * 64 + ch * 8]);
      }
#pragma unroll
      for (int mi = 0; mi < 4; ++mi)
#pragma unroll
        for (int ni = 0; ni < 4; ++ni)
          acc[mi][ni] = __builtin_amdgcn_mfma_f32_16x16x32_bf16(af[mi], bfr[ni], acc[mi][ni], 0, 0, 0);
    }
    __syncthreads();
  }

  // epilogue: C/D layout col=lane&15, row=(lane>>4)*4+reg (m89/m91 verified)
  const int rbase = c4 * 4;
#pragma unroll
  for (int mi = 0; mi < 4; ++mi) {
    const int row = m0 + wm + mi * 16 + rbase;
#pragma unroll
    for (int ni = 0; ni < 4; ++ni) {
      const int col = n0 + wn + ni * 16 + r16;
      float bv = 0.0f;
      if constexpr (BIAS) bv = bias[col];
      f32x4 v = acc[mi][ni];
#pragma unroll
      for (int r = 0; r < 4; ++r) {
        float x = v[r] + bv;
        if constexpr (PHI_COLS > 0) {
          if (col < PHI_COLS) x = (x > 0.0f) ? (x + 1.0f) : __expf(x);  // elu+1
        }
        if constexpr (OUT_BF16)
          ((unsigned short*)Cout)[(size_t)(row + r) * N + col] = f2bf(x);
        else
          ((float*)Cout)[(size_t)(row + r) * N + col] = x;
      }
    }
  }
}

// ============================================================================
// kv[m,d] = sum_n k[n,d]*v[n,m]; ksum[d] = sum_n k[n,d].
// 16 chunks of 256 n per (b,h). LDS-f32 staging (cvt once per block; r13's
// -25us win). Memory-bound at its ~8us HBM floor (r15/r17 nulls).
// ============================================================================
__global__ __launch_bounds__(256) void kv_partial_kernel(
    const unsigned short* __restrict__ qkv, float* __restrict__ kv_part,
    float* __restrict__ ksum_part) {
  __shared__ float ks32[64][64];  // [n][d] f32, 16KB
  __shared__ float vs32[64][64];  // [n][m] f32, 16KB
  const int bh = blockIdx.x;     // 48
  const int chunk = blockIdx.y;  // 16 (256 n each)
  const int b = bh / 12, h = bh % 12;
  const int t = threadIdx.x;
  const int tm = (t >> 4) * 4;
  const int td = (t & 15) * 4;
  const unsigned short* base =
      qkv + ((size_t)(b * 4096 + chunk * 256)) * 2304 + h * 64;

  f32x2 acc2[4][2] = {};
  f32x2 kss[2] = {};

  for (int sub = 0; sub < 4; ++sub) {
#pragma unroll
    for (int s = t; s < 512; s += 256) {
      const int nl = s >> 3;
      const int oct = s & 7;
      const unsigned short* row = base + (size_t)(sub * 64 + nl) * 2304 + oct * 8;
      bf16x8 ku = *reinterpret_cast<const bf16x8*>(row + 768);   // k
      bf16x8 vu = *reinterpret_cast<const bf16x8*>(row + 1536);  // v
      float* kd = &ks32[nl][oct * 8];
      float* vd = &vs32[nl][oct * 8];
#pragma unroll
      for (int j = 0; j < 8; ++j) {
        kd[j] = bf2f((unsigned short)ku[j]);
        vd[j] = bf2f((unsigned short)vu[j]);
      }
    }
    __syncthreads();
#pragma unroll 8
    for (int n = 0; n < 64; ++n) {
      float4 kf = *reinterpret_cast<const float4*>(&ks32[n][td]);
      float4 vf = *reinterpret_cast<const float4*>(&vs32[n][tm]);
      f32x2 k0; k0[0] = kf.x; k0[1] = kf.y;
      f32x2 k1; k1[0] = kf.z; k1[1] = kf.w;
      const float va[4] = {vf.x, vf.y, vf.z, vf.w};
#pragma unroll
      for (int i = 0; i < 4; ++i) {
        f32x2 vd2; vd2[0] = va[i]; vd2[1] = va[i];
        acc2[i][0] += vd2 * k0;
        acc2[i][1] += vd2 * k1;
      }
      kss[0] += k0;
      kss[1] += k1;
    }
    __syncthreads();
  }

  float* kvp = kv_part + ((size_t)(bh * 16 + chunk)) * 4096;
#pragma unroll
  for (int i = 0; i < 4; ++i) {
    float4 o;
    o.x = acc2[i][0][0]; o.y = acc2[i][0][1];
    o.z = acc2[i][1][0]; o.w = acc2[i][1][1];
    *reinterpret_cast<float4*>(&kvp[(tm + i) * 64 + td]) = o;
  }
  if (tm == 0) {
    float* ksp = ksum_part + (size_t)(bh * 16 + chunk) * 64;
    float4 o;
    o.x = kss[0][0]; o.y = kss[0][1]; o.z = kss[1][0]; o.w = kss[1][1];
    *reinterpret_cast<float4*>(&ksp[td]) = o;
  }
}

// widened reduce: grid (48,4); float4 loads; kv emitted bf16, ksum f32.
__global__ __launch_bounds__(256) void kv_reduce_kernel(
    const float* __restrict__ kv_part, const float* __restrict__ ksum_part,
    unsigned short* __restrict__ kvb, float* __restrict__ ksum) {
  const int bh = blockIdx.x;
  const int seg = blockIdx.y;
  const int t = threadIdx.x;
  const int e = seg * 1024 + t * 4;
  float4 s = {0.f, 0.f, 0.f, 0.f};
#pragma unroll
  for (int c = 0; c < 16; ++c) {
    float4 v = *reinterpret_cast<const float4*>(
        &kv_part[((size_t)(bh * 16 + c)) * 4096 + e]);
    s.x += v.x; s.y += v.y; s.z += v.z; s.w += v.w;
  }
  ushort4 o;
  o.x = f2bf(s.x); o.y = f2bf(s.y); o.z = f2bf(s.z); o.w = f2bf(s.w);
  *reinterpret_cast<ushort4*>(&kvb[(size_t)bh * 4096 + e]) = o;
  if (seg == 0 && t < 64) {
    float ss = 0.f;
#pragma unroll
    for (int c = 0; c < 16; ++c) ss += ksum_part[(size_t)(bh * 16 + c) * 64 + t];
    ksum[bh * 64 + t] = ss;
  }
}

// y[n,m] = z[n] * sum_d q[n,d] kv[m,d], z[n]=1/(q[n,:].ksum+eps), via MFMA.
__global__ __launch_bounds__(256) void y_mfma_kernel(
    const unsigned short* __restrict__ qkv, const unsigned short* __restrict__ kvb,
    const float* __restrict__ ksum, unsigned short* __restrict__ ybf) {
  __shared__ unsigned short Qs[128 * 64];
  __shared__ unsigned short KVs[64 * 64];
  __shared__ float zs[128];
  const int bh = blockIdx.x;
  const int n0 = blockIdx.y * 128;
  const int b = bh / 12, h = bh % 12;
  const int t = threadIdx.x;
  const int w = t >> 6;
  const int l = t & 63;
  const int r16 = l & 15;
  const int c4 = l >> 4;

  const int srow = t >> 3;
  const int schunk = (t & 7) ^ ((t >> 3) & 7);
  const unsigned short* gQ =
      qkv + ((size_t)(b * 4096 + n0 + srow)) * 2304 + h * 64 + schunk * 8;
  const unsigned short* gKV = kvb + (size_t)bh * 4096 + srow * 64 + schunk * 8;
  const int lbase = w * 512;
#pragma unroll
  for (int i = 0; i < 4; ++i)
    GLOAD_LDS16(gQ + (size_t)i * 32 * 2304, &Qs[lbase + i * 2048]);
#pragma unroll
  for (int i = 0; i < 2; ++i)
    GLOAD_LDS16(gKV + i * 32 * 64, &KVs[lbase + i * 2048]);
  __syncthreads();

  const int wr = w * 32;
  f32x4 acc[2][4] = {};
#pragma unroll
  for (int kk = 0; kk < 2; ++kk) {
    bf16x8 af[2], bfr[4];
#pragma unroll
    for (int mi = 0; mi < 2; ++mi) {
      const int R = wr + mi * 16 + r16;
      const int ch = (kk * 4 + c4) ^ (R & 7);
      af[mi] = *reinterpret_cast<const bf16x8*>(&Qs[R * 64 + ch * 8]);
    }
#pragma unroll
    for (int ni = 0; ni < 4; ++ni) {
      const int R = ni * 16 + r16;
      const int ch = (kk * 4 + c4) ^ (R & 7);
      bfr[ni] = *reinterpret_cast<const bf16x8*>(&KVs[R * 64 + ch * 8]);
    }
#pragma unroll
    for (int mi = 0; mi < 2; ++mi)
#pragma unroll
      for (int ni = 0; ni < 4; ++ni)
        acc[mi][ni] = __builtin_amdgcn_mfma_f32_16x16x32_bf16(af[mi], bfr[ni], acc[mi][ni], 0, 0, 0);
  }

  if (t < 128) {
    const float* ks = ksum + bh * 64;
    float s = 0.f;
#pragma unroll
    for (int c = 0; c < 8; ++c) {
      bf16x8 qv = *reinterpret_cast<const bf16x8*>(&Qs[t * 64 + ((c ^ (t & 7)) * 8)]);
#pragma unroll
      for (int j = 0; j < 8; ++j) s += bf2f((unsigned short)qv[j]) * ks[c * 8 + j];
    }
    zs[t] = 1.0f / (s + 1e-6f);
  }
  __syncthreads();

  unsigned short* ybase = ybf + ((size_t)(b * 4096 + n0)) * 768 + h * 64;
#pragma unroll
  for (int mi = 0; mi < 2; ++mi) {
#pragma unroll
    for (int ni = 0; ni < 4; ++ni) {
      const int col = ni * 16 + r16;
      f32x4 v = acc[mi][ni];
#pragma unroll
      for (int r = 0; r < 4; ++r) {
        const int row = wr + mi * 16 + c4 * 4 + r;
        ybase[(size_t)row * 768 + col] = f2bf(v[r] * zs[row]);
      }
    }
  }
}

extern "C" void kernel_launch(void* const* d_in, const int* in_sizes, int n_in,
                              void* d_out, int out_size, void* d_ws, size_t ws_size,
                              hipStream_t stream) {
  const float* x = (const float*)d_in[0];
  const float* Wqkv = (const float*)d_in[1];
  const float* Wproj = (const float*)d_in[2];
  const float* bproj = (const float*)d_in[3];
  float* out = (float*)d_out;

  const int M = 16384;
  const int C = 768;
  const int N1 = 2304;

  char* ws = (char*)d_ws;
  size_t off = 0;
  unsigned short* xb = (unsigned short*)(ws + off);  off += (size_t)M * C * 2;
  unsigned short* wqb = (unsigned short*)(ws + off); off += (size_t)N1 * C * 2;
  unsigned short* wpb = (unsigned short*)(ws + off); off += (size_t)C * C * 2;
  unsigned short* qkvb = (unsigned short*)(ws + off); off += (size_t)M * N1 * 2;
  unsigned short* kvb = (unsigned short*)(ws + off); off += (size_t)48 * 4096 * 2;
  float* ksum = (float*)(ws + off);      off += (size_t)48 * 64 * 4;
  unsigned short* yb = (unsigned short*)(ws + off); off += (size_t)M * C * 2;
  float* ksum_part = (float*)(ws + off); off += (size_t)48 * 16 * 64 * 4;
  float* kv_part = (float*)xb;  // overlays xb (dead after GEMM1); 12.6MB < 25MB

  const int na4 = M * C / 4, nb4 = N1 * C / 4, nc4 = C * C / 4;
  cast3_kernel<<<(na4 + nb4 + nc4 + 255) / 256, 256, 0, stream>>>(
      x, Wqkv, Wproj, xb, wqb, wpb, na4, nb4, nc4);

  // qkv = x @ Wqkv^T, phi fused on q,k columns, bf16 out
  gemm128<1536, true, false>
      <<<dim3(N1 / 128, M / 128), 256, 0, stream>>>(xb, wqb, qkvb, nullptr, M, N1, C);

  kv_partial_kernel<<<dim3(48, 16), 256, 0, stream>>>(qkvb, kv_part, ksum_part);
  kv_reduce_kernel<<<dim3(48, 4), 256, 0, stream>>>(kv_part, ksum_part, kvb, ksum);
  y_mfma_kernel<<<dim3(48, 32), 256, 0, stream>>>(qkvb, kvb, ksum, yb);

  // out = y @ Wproj^T + b, fp32 out
  gemm128<0, false, true>
      <<<dim3(C / 128, M / 128), 256, 0, stream>>>(yb, wpb, out, bproj, M, C, C);
}